// Round 4
// baseline (1649.089 us; speedup 1.0000x reference)
//
#include <hip/hip_runtime.h>
#include <hip/hip_bf16.h>
#include <math.h>

#define B_ 8
#define T_ 8192
#define V_ 256
#define EB_ 64
#define E_ 64
#define H_ 512
#define SS_ 32
#define FEATP_ 160   // padded feature dim (real 132, zero-padded to 160 = 5*32)
#define NCH_ 256
#define CHUNK_ 32

typedef __attribute__((ext_vector_type(8))) short bf8;     // 8 bf16 = 4 VGPRs (MFMA A/B frag)
typedef __attribute__((ext_vector_type(16))) float accv;   // MFMA 32x32 C/D frag

#define AS1(p) (__attribute__((address_space(1))) void*)(void*)(p)
#define AS3(p) (__attribute__((address_space(3))) void*)(void*)(p)

__device__ __forceinline__ float silu_f(float x) { return x / (1.0f + expf(-x)); }
__device__ __forceinline__ float sigm_f(float x) { return 1.0f / (1.0f + expf(-x)); }
__device__ __forceinline__ float bf2f(__hip_bfloat16 v) { return __bfloat162float(v); }
__device__ __forceinline__ __hip_bfloat16 f2bf(float v) { return __float2bfloat16(v); }

// ===================== MFMA 128x128-tile GEMM core =====================
template <int KD>
__device__ __forceinline__ void mm128(const __hip_bfloat16* __restrict__ A,
                                      const __hip_bfloat16* __restrict__ Wt,
                                      int m0, int n0, accv (&acc)[2][2]) {
    __shared__ __align__(16) ushort lA[128 * 32];
    __shared__ __align__(16) ushort lB[128 * 32];
    int tid = threadIdx.x;
    int lane = tid & 63, w = tid >> 6;
    int wm = w & 1, wn = w >> 1;
    int c0 = w * 128 + lane;
    int c1 = c0 + 64;
    const ushort* Ab = (const ushort*)A;
    const ushort* Bb = (const ushort*)Wt;
    const ushort* gA0 = Ab + (size_t)(m0 + (c0 >> 2)) * KD + (c0 & 3) * 8;
    const ushort* gA1 = Ab + (size_t)(m0 + (c1 >> 2)) * KD + (c1 & 3) * 8;
    const ushort* gB0 = Bb + (size_t)(n0 + (c0 >> 2)) * KD + (c0 & 3) * 8;
    const ushort* gB1 = Bb + (size_t)(n0 + (c1 >> 2)) * KD + (c1 & 3) * 8;
    ushort* dA0 = &lA[(w * 128) * 8];
    ushort* dA1 = &lA[(w * 128 + 64) * 8];
    ushort* dB0 = &lB[(w * 128) * 8];
    ushort* dB1 = &lB[(w * 128 + 64) * 8];
    const ushort* pa = &lA[(64 * wm + (lane & 31)) * 32 + (lane >> 5) * 8];
    const ushort* pb = &lB[(64 * wn + (lane & 31)) * 32 + (lane >> 5) * 8];

    for (int kt = 0; kt < KD; kt += 32) {
        __builtin_amdgcn_global_load_lds(AS1(gA0 + kt), AS3(dA0), 16, 0, 0);
        __builtin_amdgcn_global_load_lds(AS1(gA1 + kt), AS3(dA1), 16, 0, 0);
        __builtin_amdgcn_global_load_lds(AS1(gB0 + kt), AS3(dB0), 16, 0, 0);
        __builtin_amdgcn_global_load_lds(AS1(gB1 + kt), AS3(dB1), 16, 0, 0);
        __syncthreads();
#pragma unroll
        for (int ks = 0; ks < 2; ks++) {
            bf8 a0 = *(const bf8*)(pa + ks * 16);
            bf8 a1 = *(const bf8*)(pa + 32 * 32 + ks * 16);
            bf8 b0 = *(const bf8*)(pb + ks * 16);
            bf8 b1 = *(const bf8*)(pb + 32 * 32 + ks * 16);
            acc[0][0] = __builtin_amdgcn_mfma_f32_32x32x16_bf16(a0, b0, acc[0][0], 0, 0, 0);
            acc[0][1] = __builtin_amdgcn_mfma_f32_32x32x16_bf16(a0, b1, acc[0][1], 0, 0, 0);
            acc[1][0] = __builtin_amdgcn_mfma_f32_32x32x16_bf16(a1, b0, acc[1][0], 0, 0, 0);
            acc[1][1] = __builtin_amdgcn_mfma_f32_32x32x16_bf16(a1, b1, acc[1][1], 0, 0, 0);
        }
        __syncthreads();
    }
}

__device__ __forceinline__ void zero_acc(accv (&acc)[2][2]) {
#pragma unroll
    for (int i = 0; i < 2; i++)
#pragma unroll
        for (int j = 0; j < 2; j++)
#pragma unroll
            for (int r = 0; r < 16; r++) acc[i][j][r] = 0.0f;
}

#define CD_ROW(r, lane) (((r) & 3) + 8 * ((r) >> 2) + 4 * ((lane) >> 5))

// ---------------- MLP residual block: hout = hin + silu(hin @ W + b)
__global__ __launch_bounds__(256) void k_mlp_mfma(const __hip_bfloat16* __restrict__ hin,
                                                  const __hip_bfloat16* __restrict__ Wt,
                                                  const float* __restrict__ bias,
                                                  __hip_bfloat16* __restrict__ hout) {
    accv acc[2][2];
    zero_acc(acc);
    int lane = threadIdx.x & 63, w = threadIdx.x >> 6, wm = w & 1, wn = w >> 1;
    int m0 = blockIdx.x * 128, n0 = blockIdx.y * 128;
    mm128<H_>(hin, Wt, m0, n0, acc);
#pragma unroll
    for (int i = 0; i < 2; i++)
#pragma unroll
        for (int j = 0; j < 2; j++) {
            int col = n0 + 64 * wn + 32 * j + (lane & 31);
            float bv = bias[col];
#pragma unroll
            for (int r = 0; r < 16; r++) {
                int row = m0 + 64 * wm + 32 * i + CD_ROW(r, lane);
                float v = acc[i][j][r] + bv;
                float res = bf2f(hin[(size_t)row * H_ + col]);
                hout[(size_t)row * H_ + col] = f2bf(res + silu_f(v));
            }
        }
}

// ---------------- Win: hb = bf16(silu(featb @ Win + b_in)), KD=160
__global__ __launch_bounds__(256) void k_win_mfma(const __hip_bfloat16* __restrict__ featb,
                                                  const __hip_bfloat16* __restrict__ Wt,
                                                  const float* __restrict__ bias,
                                                  __hip_bfloat16* __restrict__ hb) {
    accv acc[2][2];
    zero_acc(acc);
    int lane = threadIdx.x & 63, w = threadIdx.x >> 6, wm = w & 1, wn = w >> 1;
    int m0 = blockIdx.x * 128, n0 = blockIdx.y * 128;
    mm128<FEATP_>(featb, Wt, m0, n0, acc);
#pragma unroll
    for (int i = 0; i < 2; i++)
#pragma unroll
        for (int j = 0; j < 2; j++) {
            int col = n0 + 64 * wn + 32 * j + (lane & 31);
            float bv = bias[col];
#pragma unroll
            for (int r = 0; r < 16; r++) {
                int row = m0 + 64 * wm + 32 * i + CD_ROW(r, lane);
                hb[(size_t)row * H_ + col] = f2bf(silu_f(acc[i][j][r] + bv));
            }
        }
}

// ---------------- Out: out = hb @ Wout + bout (fp32 out, N=256)
__global__ __launch_bounds__(256) void k_out_mfma(const __hip_bfloat16* __restrict__ hb,
                                                  const __hip_bfloat16* __restrict__ Wt,
                                                  const float* __restrict__ bout,
                                                  float* __restrict__ out) {
    accv acc[2][2];
    zero_acc(acc);
    int lane = threadIdx.x & 63, w = threadIdx.x >> 6, wm = w & 1, wn = w >> 1;
    int m0 = blockIdx.x * 128, n0 = blockIdx.y * 128;
    mm128<H_>(hb, Wt, m0, n0, acc);
#pragma unroll
    for (int i = 0; i < 2; i++)
#pragma unroll
        for (int j = 0; j < 2; j++) {
            int col = n0 + 64 * wn + 32 * j + (lane & 31);
            float bv = bout[col];
#pragma unroll
            for (int r = 0; r < 16; r++) {
                int row = m0 + 64 * wm + 32 * i + CD_ROW(r, lane);
                out[(size_t)row * V_ + col] = acc[i][j][r] + bv;
            }
        }
}

// ---------------- gates/drive: [g|i] = hb @ [Wg|Wi]; tile 256x64, K=512
__global__ __launch_bounds__(256) void k_gates_mfma(const __hip_bfloat16* __restrict__ hb,
                                                    const __hip_bfloat16* __restrict__ Wt_gd,
                                                    const float* __restrict__ bg,
                                                    const float* __restrict__ bi,
                                                    float* __restrict__ gates,
                                                    float* __restrict__ drive) {
    __shared__ __align__(16) ushort lA[256 * 32];
    __shared__ __align__(16) ushort lB[64 * 32];
    int tid = threadIdx.x, lane = tid & 63, w = tid >> 6;
    int m0 = blockIdx.x * 256;
    accv acc[2][2];
    zero_acc(acc);
    const ushort* Ab = (const ushort*)hb;
    const ushort* Bb = (const ushort*)Wt_gd;
    const ushort* pa = &lA[(64 * w + (lane & 31)) * 32 + (lane >> 5) * 8];
    const ushort* pb = &lB[((lane & 31)) * 32 + (lane >> 5) * 8];
    int cb = w * 64 + lane;
    const ushort* gB = Bb + (size_t)(cb >> 2) * H_ + (cb & 3) * 8;
    for (int kt = 0; kt < H_; kt += 32) {
#pragma unroll
        for (int j = 0; j < 4; j++) {
            int c = w * 256 + j * 64 + lane;
            __builtin_amdgcn_global_load_lds(
                AS1(Ab + (size_t)(m0 + (c >> 2)) * H_ + (c & 3) * 8 + kt),
                AS3(&lA[(w * 256 + j * 64) * 8]), 16, 0, 0);
        }
        __builtin_amdgcn_global_load_lds(AS1(gB + kt), AS3(&lB[(w * 64) * 8]), 16, 0, 0);
        __syncthreads();
#pragma unroll
        for (int ks = 0; ks < 2; ks++) {
            bf8 a0 = *(const bf8*)(pa + ks * 16);
            bf8 a1 = *(const bf8*)(pa + 32 * 32 + ks * 16);
            bf8 b0 = *(const bf8*)(pb + ks * 16);
            bf8 b1 = *(const bf8*)(pb + 32 * 32 + ks * 16);
            acc[0][0] = __builtin_amdgcn_mfma_f32_32x32x16_bf16(a0, b0, acc[0][0], 0, 0, 0);
            acc[0][1] = __builtin_amdgcn_mfma_f32_32x32x16_bf16(a0, b1, acc[0][1], 0, 0, 0);
            acc[1][0] = __builtin_amdgcn_mfma_f32_32x32x16_bf16(a1, b0, acc[1][0], 0, 0, 0);
            acc[1][1] = __builtin_amdgcn_mfma_f32_32x32x16_bf16(a1, b1, acc[1][1], 0, 0, 0);
        }
        __syncthreads();
    }
    int c = lane & 31;
    float bgv = bg[c], biv = bi[c];
#pragma unroll
    for (int i = 0; i < 2; i++)
#pragma unroll
        for (int r = 0; r < 16; r++) {
            int row = m0 + 64 * w + 32 * i + CD_ROW(r, lane);
            float g = sigm_f(acc[i][0][r] + bgv);
            float d = (1.0f - g) * (acc[i][1][r] + biv);
            gates[(size_t)row * SS_ + c] = g;
            drive[(size_t)row * SS_ + c] = d;
        }
}

// ===================== weight prep: bf16 + transpose =====================
__global__ __launch_bounds__(256) void k_prep_w(const float* __restrict__ mlp_w,
                                                const float* __restrict__ Wout,
                                                const float* __restrict__ Win,
                                                const float* __restrict__ Wg,
                                                const float* __restrict__ Wi,
                                                __hip_bfloat16* __restrict__ Wt_mlp,
                                                __hip_bfloat16* __restrict__ Wt_out,
                                                __hip_bfloat16* __restrict__ Wt_win,
                                                __hip_bfloat16* __restrict__ Wt_gd) {
    int idx = blockIdx.x * 256 + threadIdx.x;
    if (idx < 786432) {
        int l = idx >> 18, rem = idx & 262143;
        int n = rem >> 9, k = rem & 511;
        Wt_mlp[idx] = f2bf(mlp_w[l * 262144 + k * 512 + n]);
    } else if (idx < 786432 + 131072) {
        int rem = idx - 786432;
        int n = rem >> 9, k = rem & 511;
        Wt_out[rem] = f2bf(Wout[k * 256 + n]);
    } else if (idx < 786432 + 131072 + 81920) {
        int rem = idx - (786432 + 131072);
        int n = rem / 160, k = rem % 160;
        Wt_win[rem] = f2bf(k < 132 ? Win[k * 512 + n] : 0.0f);
    } else if (idx < 786432 + 131072 + 81920 + 32768) {
        int rem = idx - (786432 + 131072 + 81920);
        int n = rem >> 9, k = rem & 511;
        Wt_gd[rem] = f2bf(n < 32 ? Wg[k * 32 + n] : Wi[k * 32 + (n - 32)]);
    }
}

// ===================== token features =====================
__global__ __launch_bounds__(256) void k_token_feats(
    const int* __restrict__ chars, const float* __restrict__ emb_byte,
    const float* __restrict__ hash_tables, const float* __restrict__ Wq,
    const float* __restrict__ bq, __hip_bfloat16* __restrict__ featb,
    float* __restrict__ hfpre) {
    int wave = threadIdx.x >> 6, lane = threadIdx.x & 63;
    int token = blockIdx.x * 4 + wave;
    int t = token & (T_ - 1);
    int b = token >> 13;
    const int* crow = chars + b * T_;
    int cj = 0;
    if (lane < 16 && (t - lane) >= 0) cj = crow[t - lane];
    int cv[16];
#pragma unroll
    for (int j = 0; j < 16; j++) cv[j] = __shfl(cj, j, 64);
    int acc = 0;
    int hidx[4];
#pragma unroll
    for (int j = 0; j < 16; j++) {
        acc += cv[j] * (1 + 256 * j);
        if (j == 1) hidx[0] = acc & 4095;
        if (j == 3) hidx[1] = acc & 4095;
        if (j == 7) hidx[2] = acc & 4095;
        if (j == 15) hidx[3] = acc & 4095;
    }
    float be = emb_byte[cv[0] * EB_ + lane];
    float se[4];
#pragma unroll
    for (int s = 0; s < 4; s++) se[s] = hash_tables[(s * 4096 + hidx[s]) * E_ + lane];
    float q = bq[lane];
#pragma unroll
    for (int k = 0; k < 64; k++) q += __shfl(be, k, 64) * Wq[k * 64 + lane];
    float sc[4];
#pragma unroll
    for (int s = 0; s < 4; s++) {
        float v = q * se[s];
#pragma unroll
        for (int off = 32; off; off >>= 1) v += __shfl_xor(v, off, 64);
        sc[s] = v * 0.125f;
    }
    float mx = fmaxf(fmaxf(sc[0], sc[1]), fmaxf(sc[2], sc[3]));
    float w0 = expf(sc[0] - mx), w1 = expf(sc[1] - mx), w2 = expf(sc[2] - mx), w3 = expf(sc[3] - mx);
    float inv = 1.0f / (w0 + w1 + w2 + w3);
    float hf = (w0 * se[0] + w1 * se[1] + w2 * se[2] + w3 * se[3]) * inv;
    featb[(size_t)token * FEATP_ + lane] = f2bf(be);
    hfpre[(size_t)token * E_ + lane] = hf;
    if (lane < 32) {
        float m = 0.0f;
        if (lane < 4) {
            int k = 1 << lane;
            m = (t >= k && cv[0] == cv[k]) ? 1.0f : 0.0f;
        }
        featb[(size_t)token * FEATP_ + 128 + lane] = f2bf(m);
    }
}

// ===================== conv -> featb[64:128] =====================
__global__ __launch_bounds__(256) void k_conv(
    const float* __restrict__ hfpre, const float* __restrict__ conv_w,
    const float* __restrict__ conv_b, __hip_bfloat16* __restrict__ featb) {
    int idx = blockIdx.x * 256 + threadIdx.x;
    int e = idx & 63;
    int bt = idx >> 6;
    int t = bt & (T_ - 1);
    float acc = conv_b[e];
#pragma unroll
    for (int k = 0; k < 4; k++) {
        int tt = t - 3 + k;
        if (tt >= 0) acc += hfpre[(size_t)(bt - 3 + k) * E_ + e] * conv_w[e * 4 + k];
    }
    featb[(size_t)bt * FEATP_ + 64 + e] = f2bf(silu_f(acc));
}

// ===================== scan chain =====================
__global__ __launch_bounds__(256) void k_chunk_ab(
    const float* __restrict__ gates, const float* __restrict__ drive,
    float* __restrict__ chA, float* __restrict__ chB) {
    int gid = blockIdx.x * 256 + threadIdx.x;
    int s = gid & 31;
    int n = (gid >> 5) & (NCH_ - 1);
    int b = gid >> 13;
    int base = (b * T_ + n * CHUNK_) * SS_ + s;
    float suml = 0.f, cum_wb = 0.f, cum_a = 1.f;
    for (int i = 0; i < CHUNK_; i++) {
        float g = gates[base + i * SS_];
        float d = drive[base + i * SS_];
        suml += logf(fmaxf(g, 1e-6f));
        cum_a = expf(suml);
        cum_wb += d / fmaxf(cum_a, 1e-8f);
    }
    chA[gid] = cum_a;
    chB[gid] = cum_a * cum_wb;
}

__global__ void k_chunk_scan(const float* __restrict__ chA, const float* __restrict__ chB,
                             float* __restrict__ chH) {
    int tid = threadIdx.x;     // 256 = B*SS
    int b = tid >> 5, s = tid & 31;
    const float* pA = chA + (size_t)b * NCH_ * SS_ + s;
    const float* pB = chB + (size_t)b * NCH_ * SS_ + s;
    float* pH = chH + (size_t)b * NCH_ * SS_ + s;
    float hc = 0.f;
    for (int n = 0; n < NCH_; n += 8) {
        float a[8], bb[8];
#pragma unroll
        for (int i = 0; i < 8; i++) {
            a[i] = pA[(n + i) * SS_];
            bb[i] = pB[(n + i) * SS_];
        }
#pragma unroll
        for (int i = 0; i < 8; i++) {
            pH[(n + i) * SS_] = hc;
            hc = a[i] * hc + bb[i];
        }
    }
}

__global__ __launch_bounds__(256) void k_states(
    const float* __restrict__ gates, const float* __restrict__ drive,
    const float* __restrict__ chH, float* __restrict__ states) {
    int gid = blockIdx.x * 256 + threadIdx.x;
    int s = gid & 31;
    int n = (gid >> 5) & (NCH_ - 1);
    int b = gid >> 13;
    int base = (b * T_ + n * CHUNK_) * SS_ + s;
    float hc = chH[gid];
    float suml = 0.f, cum_wb = 0.f;
    for (int i = 0; i < CHUNK_; i++) {
        float g = gates[base + i * SS_];
        float d = drive[base + i * SS_];
        suml += logf(fmaxf(g, 1e-6f));
        float cum_a = expf(suml);
        cum_wb += d / fmaxf(cum_a, 1e-8f);
        states[base + i * SS_] = cum_a * (hc + cum_wb);
    }
}

// ===================== LN(h + states@Wo + bo): 512 thr, 1 col/thread, 16 tok/block
__global__ __launch_bounds__(512) void k_wo_ln(
    const float* __restrict__ states, const float* __restrict__ Wo, const float* __restrict__ bo,
    const float* __restrict__ ln_g, const float* __restrict__ ln_b,
    __hip_bfloat16* __restrict__ hb) {
    __shared__ float sst[16 * SS_];   // 2 KB, broadcast reads
    __shared__ float red[16][8][2];   // 1 KB
    int tid = threadIdx.x;            // 0..511 = output column j
    int bt0 = blockIdx.x * 16;
    sst[tid] = states[(size_t)bt0 * SS_ + tid];   // 512 floats, coalesced
    float wo[SS_];
#pragma unroll
    for (int s = 0; s < SS_; s++) wo[s] = Wo[s * H_ + tid];
    float bov = bo[tid], gv = ln_g[tid], lbv = ln_b[tid];
    __syncthreads();
    float v[16];
#pragma unroll
    for (int m = 0; m < 16; m++) {
        float a = bf2f(hb[(size_t)(bt0 + m) * H_ + tid]) + bov;
#pragma unroll
        for (int s = 0; s < SS_; s++) a += sst[m * SS_ + s] * wo[s];
        v[m] = a;
    }
    int w = tid >> 6, lane = tid & 63;
#pragma unroll
    for (int m = 0; m < 16; m++) {
        float sm = v[m], sq = v[m] * v[m];
#pragma unroll
        for (int off = 32; off; off >>= 1) {
            sm += __shfl_xor(sm, off, 64);
            sq += __shfl_xor(sq, off, 64);
        }
        if (lane == 0) { red[m][w][0] = sm; red[m][w][1] = sq; }
    }
    __syncthreads();
#pragma unroll
    for (int m = 0; m < 16; m++) {
        float sm = 0.f, sq = 0.f;
#pragma unroll
        for (int ww = 0; ww < 8; ww++) { sm += red[m][ww][0]; sq += red[m][ww][1]; }
        float mu = sm * (1.0f / 512.0f);
        float var = sq * (1.0f / 512.0f) - mu * mu;
        float rstd = rsqrtf(fmaxf(var, 0.0f) + 1e-5f);
        hb[(size_t)(bt0 + m) * H_ + tid] = f2bf((v[m] - mu) * rstd * gv + lbv);
    }
}

// ===================== launch =====================
extern "C" void kernel_launch(void* const* d_in, const int* in_sizes, int n_in,
                              void* d_out, int out_size, void* d_ws, size_t ws_size,
                              hipStream_t stream) {
    (void)in_sizes; (void)n_in; (void)out_size; (void)ws_size;
    const int*   chars       = (const int*)  d_in[0];
    const float* emb_byte    = (const float*)d_in[1];
    const float* hash_tables = (const float*)d_in[2];
    const float* Wq          = (const float*)d_in[3];
    const float* bq          = (const float*)d_in[4];
    const float* conv_w      = (const float*)d_in[5];
    const float* conv_b      = (const float*)d_in[6];
    const float* Win         = (const float*)d_in[7];
    const float* b_in        = (const float*)d_in[8];
    const float* Wg          = (const float*)d_in[9];
    const float* bg          = (const float*)d_in[10];
    const float* Wi          = (const float*)d_in[11];
    const float* bi          = (const float*)d_in[12];
    const float* Wo          = (const float*)d_in[13];
    const float* bo          = (const float*)d_in[14];
    const float* ln_g        = (const float*)d_in[15];
    const float* ln_b        = (const float*)d_in[16];
    const float* mlp_w       = (const float*)d_in[17];
    const float* mlp_b       = (const float*)d_in[18];
    const float* Wout        = (const float*)d_in[19];
    const float* bout        = (const float*)d_in[20];
    float* out = (float*)d_out;

    const size_t NTOK = (size_t)B_ * T_;  // 65536
    char* p = (char*)d_ws;
    auto alloc = [&](size_t bytes) { void* r = (void*)p; p += (bytes + 255) & ~(size_t)255; return r; };
    __hip_bfloat16* featb = (__hip_bfloat16*)alloc(NTOK * FEATP_ * 2);
    float*          hfpre = (float*)alloc(NTOK * E_ * 4);
    __hip_bfloat16* hbA   = (__hip_bfloat16*)alloc(NTOK * H_ * 2);
    __hip_bfloat16* hbB   = (__hip_bfloat16*)alloc(NTOK * H_ * 2);
    float*          gates = (float*)alloc(NTOK * SS_ * 4);
    float*          drive = (float*)alloc(NTOK * SS_ * 4);
    float*          states= (float*)alloc(NTOK * SS_ * 4);
    float*          chA   = (float*)alloc((size_t)B_ * NCH_ * SS_ * 4);
    float*          chB   = (float*)alloc((size_t)B_ * NCH_ * SS_ * 4);
    float*          chH   = (float*)alloc((size_t)B_ * NCH_ * SS_ * 4);
    __hip_bfloat16* Wt_mlp= (__hip_bfloat16*)alloc(3 * 512 * 512 * 2);
    __hip_bfloat16* Wt_out= (__hip_bfloat16*)alloc(256 * 512 * 2);
    __hip_bfloat16* Wt_win= (__hip_bfloat16*)alloc(512 * FEATP_ * 2);
    __hip_bfloat16* Wt_gd = (__hip_bfloat16*)alloc(64 * 512 * 2);

    k_prep_w<<<4032, 256, 0, stream>>>(mlp_w, Wout, Win, Wg, Wi, Wt_mlp, Wt_out, Wt_win, Wt_gd);
    k_token_feats<<<NTOK / 4, 256, 0, stream>>>(chars, emb_byte, hash_tables, Wq, bq, featb, hfpre);
    k_conv<<<NTOK * E_ / 256, 256, 0, stream>>>(hfpre, conv_w, conv_b, featb);
    k_win_mfma<<<dim3(NTOK / 128, 4), 256, 0, stream>>>(featb, Wt_win, b_in, hbA);
    k_gates_mfma<<<NTOK / 256, 256, 0, stream>>>(hbA, Wt_gd, bg, bi, gates, drive);
    k_chunk_ab<<<B_ * NCH_ * SS_ / 256, 256, 0, stream>>>(gates, drive, chA, chB);
    k_chunk_scan<<<1, 256, 0, stream>>>(chA, chB, chH);
    k_states<<<B_ * NCH_ * SS_ / 256, 256, 0, stream>>>(gates, drive, chH, states);
    k_wo_ln<<<NTOK / 16, 512, 0, stream>>>(states, Wo, bo, ln_g, ln_b, hbA);
    k_mlp_mfma<<<dim3(NTOK / 128, 4), 256, 0, stream>>>(hbA, Wt_mlp, mlp_b, hbB);
    k_mlp_mfma<<<dim3(NTOK / 128, 4), 256, 0, stream>>>(hbB, Wt_mlp + 262144, mlp_b + 512, hbA);
    k_mlp_mfma<<<dim3(NTOK / 128, 4), 256, 0, stream>>>(hbA, Wt_mlp + 524288, mlp_b + 1024, hbB);
    k_out_mfma<<<dim3(NTOK / 128, 2), 256, 0, stream>>>(hbB, Wt_out, bout, out);
}

// Round 5
// 587.414 us; speedup vs baseline: 2.8074x; 2.8074x over previous
//
#include <hip/hip_runtime.h>
#include <hip/hip_bf16.h>
#include <math.h>

#define B_ 8
#define T_ 8192
#define V_ 256
#define EB_ 64
#define E_ 64
#define H_ 512
#define SS_ 32
#define FEATP_ 160   // padded feature dim (real 132, zero-padded to 160 = 5*32)
#define NCH_ 256
#define CHUNK_ 32

typedef __attribute__((ext_vector_type(8))) short bf8;     // 8 bf16 = 4 VGPRs (MFMA A/B frag)
typedef __attribute__((ext_vector_type(16))) float accv;   // MFMA 32x32 C/D frag

#define AS1(p) (__attribute__((address_space(1))) void*)(void*)(p)
#define AS3(p) (__attribute__((address_space(3))) void*)(void*)(p)

__device__ __forceinline__ float silu_f(float x) { return x / (1.0f + expf(-x)); }
__device__ __forceinline__ float sigm_f(float x) { return 1.0f / (1.0f + expf(-x)); }
__device__ __forceinline__ float bf2f(__hip_bfloat16 v) { return __bfloat162float(v); }
__device__ __forceinline__ __hip_bfloat16 f2bf(float v) { return __float2bfloat16(v); }
__device__ __forceinline__ float us2f(ushort u) {
    union { float f; unsigned int u32; } c; c.u32 = ((unsigned int)u) << 16; return c.f;
}
__device__ __forceinline__ ushort f2us(float v) {
    __hip_bfloat16 t = __float2bfloat16(v);
    return *reinterpret_cast<ushort*>(&t);
}

// ===================== MFMA 128x128-tile GEMM core =====================
template <int KD>
__device__ __forceinline__ void mm128(const __hip_bfloat16* __restrict__ A,
                                      const __hip_bfloat16* __restrict__ Wt,
                                      int m0, int n0, accv (&acc)[2][2]) {
    __shared__ __align__(16) ushort lA[128 * 32];
    __shared__ __align__(16) ushort lB[128 * 32];
    int tid = threadIdx.x;
    int lane = tid & 63, w = tid >> 6;
    int wm = w & 1, wn = w >> 1;
    int c0 = w * 128 + lane;
    int c1 = c0 + 64;
    const ushort* Ab = (const ushort*)A;
    const ushort* Bb = (const ushort*)Wt;
    const ushort* gA0 = Ab + (size_t)(m0 + (c0 >> 2)) * KD + (c0 & 3) * 8;
    const ushort* gA1 = Ab + (size_t)(m0 + (c1 >> 2)) * KD + (c1 & 3) * 8;
    const ushort* gB0 = Bb + (size_t)(n0 + (c0 >> 2)) * KD + (c0 & 3) * 8;
    const ushort* gB1 = Bb + (size_t)(n0 + (c1 >> 2)) * KD + (c1 & 3) * 8;
    ushort* dA0 = &lA[(w * 128) * 8];
    ushort* dA1 = &lA[(w * 128 + 64) * 8];
    ushort* dB0 = &lB[(w * 128) * 8];
    ushort* dB1 = &lB[(w * 128 + 64) * 8];
    const ushort* pa = &lA[(64 * wm + (lane & 31)) * 32 + (lane >> 5) * 8];
    const ushort* pb = &lB[(64 * wn + (lane & 31)) * 32 + (lane >> 5) * 8];

    for (int kt = 0; kt < KD; kt += 32) {
        __builtin_amdgcn_global_load_lds(AS1(gA0 + kt), AS3(dA0), 16, 0, 0);
        __builtin_amdgcn_global_load_lds(AS1(gA1 + kt), AS3(dA1), 16, 0, 0);
        __builtin_amdgcn_global_load_lds(AS1(gB0 + kt), AS3(dB0), 16, 0, 0);
        __builtin_amdgcn_global_load_lds(AS1(gB1 + kt), AS3(dB1), 16, 0, 0);
        __syncthreads();
#pragma unroll
        for (int ks = 0; ks < 2; ks++) {
            bf8 a0 = *(const bf8*)(pa + ks * 16);
            bf8 a1 = *(const bf8*)(pa + 32 * 32 + ks * 16);
            bf8 b0 = *(const bf8*)(pb + ks * 16);
            bf8 b1 = *(const bf8*)(pb + 32 * 32 + ks * 16);
            acc[0][0] = __builtin_amdgcn_mfma_f32_32x32x16_bf16(a0, b0, acc[0][0], 0, 0, 0);
            acc[0][1] = __builtin_amdgcn_mfma_f32_32x32x16_bf16(a0, b1, acc[0][1], 0, 0, 0);
            acc[1][0] = __builtin_amdgcn_mfma_f32_32x32x16_bf16(a1, b0, acc[1][0], 0, 0, 0);
            acc[1][1] = __builtin_amdgcn_mfma_f32_32x32x16_bf16(a1, b1, acc[1][1], 0, 0, 0);
        }
        __syncthreads();
    }
}

__device__ __forceinline__ void zero_acc(accv (&acc)[2][2]) {
#pragma unroll
    for (int i = 0; i < 2; i++)
#pragma unroll
        for (int j = 0; j < 2; j++)
#pragma unroll
            for (int r = 0; r < 16; r++) acc[i][j][r] = 0.0f;
}

#define CD_ROW(r, lane) (((r) & 3) + 8 * ((r) >> 2) + 4 * ((lane) >> 5))

// ---------------- MLP residual block: hout = hin + silu(hin @ W + b)
__global__ __launch_bounds__(256) void k_mlp_mfma(const __hip_bfloat16* __restrict__ hin,
                                                  const __hip_bfloat16* __restrict__ Wt,
                                                  const float* __restrict__ bias,
                                                  __hip_bfloat16* __restrict__ hout) {
    accv acc[2][2];
    zero_acc(acc);
    int lane = threadIdx.x & 63, w = threadIdx.x >> 6, wm = w & 1, wn = w >> 1;
    int m0 = blockIdx.x * 128, n0 = blockIdx.y * 128;
    mm128<H_>(hin, Wt, m0, n0, acc);
#pragma unroll
    for (int i = 0; i < 2; i++)
#pragma unroll
        for (int j = 0; j < 2; j++) {
            int col = n0 + 64 * wn + 32 * j + (lane & 31);
            float bv = bias[col];
#pragma unroll
            for (int r = 0; r < 16; r++) {
                int row = m0 + 64 * wm + 32 * i + CD_ROW(r, lane);
                float v = acc[i][j][r] + bv;
                float res = bf2f(hin[(size_t)row * H_ + col]);
                hout[(size_t)row * H_ + col] = f2bf(res + silu_f(v));
            }
        }
}

// ---------------- Win: hb = bf16(silu(featb @ Win + b_in)), KD=160
__global__ __launch_bounds__(256) void k_win_mfma(const __hip_bfloat16* __restrict__ featb,
                                                  const __hip_bfloat16* __restrict__ Wt,
                                                  const float* __restrict__ bias,
                                                  __hip_bfloat16* __restrict__ hb) {
    accv acc[2][2];
    zero_acc(acc);
    int lane = threadIdx.x & 63, w = threadIdx.x >> 6, wm = w & 1, wn = w >> 1;
    int m0 = blockIdx.x * 128, n0 = blockIdx.y * 128;
    mm128<FEATP_>(featb, Wt, m0, n0, acc);
#pragma unroll
    for (int i = 0; i < 2; i++)
#pragma unroll
        for (int j = 0; j < 2; j++) {
            int col = n0 + 64 * wn + 32 * j + (lane & 31);
            float bv = bias[col];
#pragma unroll
            for (int r = 0; r < 16; r++) {
                int row = m0 + 64 * wm + 32 * i + CD_ROW(r, lane);
                hb[(size_t)row * H_ + col] = f2bf(silu_f(acc[i][j][r] + bv));
            }
        }
}

// ---------------- womm: tmp = hb + states_bf @ Wo^T + bo  (K=32 single tile)
__global__ __launch_bounds__(256) void k_womm(const __hip_bfloat16* __restrict__ states_bf,
                                              const __hip_bfloat16* __restrict__ Wt_wo,
                                              const float* __restrict__ bo,
                                              const __hip_bfloat16* __restrict__ hb,
                                              __hip_bfloat16* __restrict__ tmp) {
    accv acc[2][2];
    zero_acc(acc);
    int lane = threadIdx.x & 63, w = threadIdx.x >> 6, wm = w & 1, wn = w >> 1;
    int m0 = blockIdx.x * 128, n0 = blockIdx.y * 128;
    mm128<SS_>(states_bf, Wt_wo, m0, n0, acc);
#pragma unroll
    for (int i = 0; i < 2; i++)
#pragma unroll
        for (int j = 0; j < 2; j++) {
            int col = n0 + 64 * wn + 32 * j + (lane & 31);
            float bv = bo[col];
#pragma unroll
            for (int r = 0; r < 16; r++) {
                int row = m0 + 64 * wm + 32 * i + CD_ROW(r, lane);
                float res = bf2f(hb[(size_t)row * H_ + col]);
                tmp[(size_t)row * H_ + col] = f2bf(res + acc[i][j][r] + bv);
            }
        }
}

// ---------------- LN: one wave per token, 8 cols/lane
__global__ __launch_bounds__(256) void k_ln(const __hip_bfloat16* __restrict__ tmp,
                                            const float* __restrict__ ln_g,
                                            const float* __restrict__ ln_b,
                                            __hip_bfloat16* __restrict__ hb) {
    int wave = threadIdx.x >> 6, lane = threadIdx.x & 63;
    int token = blockIdx.x * 4 + wave;
    const ushort* row = (const ushort*)(tmp + (size_t)token * H_) + lane * 8;
    bf8 xv = *(const bf8*)row;
    float x[8];
    float sm = 0.f, sq = 0.f;
#pragma unroll
    for (int i = 0; i < 8; i++) {
        x[i] = us2f((ushort)xv[i]);
        sm += x[i];
        sq += x[i] * x[i];
    }
#pragma unroll
    for (int off = 32; off; off >>= 1) {
        sm += __shfl_xor(sm, off, 64);
        sq += __shfl_xor(sq, off, 64);
    }
    float mu = sm * (1.0f / 512.0f);
    float var = sq * (1.0f / 512.0f) - mu * mu;
    float rstd = rsqrtf(fmaxf(var, 0.0f) + 1e-5f);
    float4 g0 = *(const float4*)(ln_g + lane * 8);
    float4 g1 = *(const float4*)(ln_g + lane * 8 + 4);
    float4 b0 = *(const float4*)(ln_b + lane * 8);
    float4 b1 = *(const float4*)(ln_b + lane * 8 + 4);
    float gg[8] = {g0.x, g0.y, g0.z, g0.w, g1.x, g1.y, g1.z, g1.w};
    float bb[8] = {b0.x, b0.y, b0.z, b0.w, b1.x, b1.y, b1.z, b1.w};
    bf8 o;
#pragma unroll
    for (int i = 0; i < 8; i++) o[i] = (short)f2us((x[i] - mu) * rstd * gg[i] + bb[i]);
    *(bf8*)((ushort*)(hb + (size_t)token * H_) + lane * 8) = o;
}

// ---------------- Out: out = hb @ Wout + bout (fp32 out, N=256)
__global__ __launch_bounds__(256) void k_out_mfma(const __hip_bfloat16* __restrict__ hb,
                                                  const __hip_bfloat16* __restrict__ Wt,
                                                  const float* __restrict__ bout,
                                                  float* __restrict__ out) {
    accv acc[2][2];
    zero_acc(acc);
    int lane = threadIdx.x & 63, w = threadIdx.x >> 6, wm = w & 1, wn = w >> 1;
    int m0 = blockIdx.x * 128, n0 = blockIdx.y * 128;
    mm128<H_>(hb, Wt, m0, n0, acc);
#pragma unroll
    for (int i = 0; i < 2; i++)
#pragma unroll
        for (int j = 0; j < 2; j++) {
            int col = n0 + 64 * wn + 32 * j + (lane & 31);
            float bv = bout[col];
#pragma unroll
            for (int r = 0; r < 16; r++) {
                int row = m0 + 64 * wm + 32 * i + CD_ROW(r, lane);
                out[(size_t)row * V_ + col] = acc[i][j][r] + bv;
            }
        }
}

// ---------------- gates/drive: [g|i] = hb @ [Wg|Wi]; tile 256x64, K=512
__global__ __launch_bounds__(256) void k_gates_mfma(const __hip_bfloat16* __restrict__ hb,
                                                    const __hip_bfloat16* __restrict__ Wt_gd,
                                                    const float* __restrict__ bg,
                                                    const float* __restrict__ bi,
                                                    float* __restrict__ gates,
                                                    float* __restrict__ drive) {
    __shared__ __align__(16) ushort lA[256 * 32];
    __shared__ __align__(16) ushort lB[64 * 32];
    int tid = threadIdx.x, lane = tid & 63, w = tid >> 6;
    int m0 = blockIdx.x * 256;
    accv acc[2][2];
    zero_acc(acc);
    const ushort* Ab = (const ushort*)hb;
    const ushort* Bb = (const ushort*)Wt_gd;
    const ushort* pa = &lA[(64 * w + (lane & 31)) * 32 + (lane >> 5) * 8];
    const ushort* pb = &lB[((lane & 31)) * 32 + (lane >> 5) * 8];
    int cb = w * 64 + lane;
    const ushort* gB = Bb + (size_t)(cb >> 2) * H_ + (cb & 3) * 8;
    for (int kt = 0; kt < H_; kt += 32) {
#pragma unroll
        for (int j = 0; j < 4; j++) {
            int c = w * 256 + j * 64 + lane;
            __builtin_amdgcn_global_load_lds(
                AS1(Ab + (size_t)(m0 + (c >> 2)) * H_ + (c & 3) * 8 + kt),
                AS3(&lA[(w * 256 + j * 64) * 8]), 16, 0, 0);
        }
        __builtin_amdgcn_global_load_lds(AS1(gB + kt), AS3(&lB[(w * 64) * 8]), 16, 0, 0);
        __syncthreads();
#pragma unroll
        for (int ks = 0; ks < 2; ks++) {
            bf8 a0 = *(const bf8*)(pa + ks * 16);
            bf8 a1 = *(const bf8*)(pa + 32 * 32 + ks * 16);
            bf8 b0 = *(const bf8*)(pb + ks * 16);
            bf8 b1 = *(const bf8*)(pb + 32 * 32 + ks * 16);
            acc[0][0] = __builtin_amdgcn_mfma_f32_32x32x16_bf16(a0, b0, acc[0][0], 0, 0, 0);
            acc[0][1] = __builtin_amdgcn_mfma_f32_32x32x16_bf16(a0, b1, acc[0][1], 0, 0, 0);
            acc[1][0] = __builtin_amdgcn_mfma_f32_32x32x16_bf16(a1, b0, acc[1][0], 0, 0, 0);
            acc[1][1] = __builtin_amdgcn_mfma_f32_32x32x16_bf16(a1, b1, acc[1][1], 0, 0, 0);
        }
        __syncthreads();
    }
    int c = lane & 31;
    float bgv = bg[c], biv = bi[c];
#pragma unroll
    for (int i = 0; i < 2; i++)
#pragma unroll
        for (int r = 0; r < 16; r++) {
            int row = m0 + 64 * w + 32 * i + CD_ROW(r, lane);
            float g = sigm_f(acc[i][0][r] + bgv);
            float d = (1.0f - g) * (acc[i][1][r] + biv);
            gates[(size_t)row * SS_ + c] = g;
            drive[(size_t)row * SS_ + c] = d;
        }
}

// ===================== weight prep: bf16 + transpose =====================
__global__ __launch_bounds__(256) void k_prep_w(const float* __restrict__ mlp_w,
                                                const float* __restrict__ Wout,
                                                const float* __restrict__ Win,
                                                const float* __restrict__ Wg,
                                                const float* __restrict__ Wi,
                                                const float* __restrict__ Wo,
                                                __hip_bfloat16* __restrict__ Wt_mlp,
                                                __hip_bfloat16* __restrict__ Wt_out,
                                                __hip_bfloat16* __restrict__ Wt_win,
                                                __hip_bfloat16* __restrict__ Wt_gd,
                                                __hip_bfloat16* __restrict__ Wt_wo) {
    int idx = blockIdx.x * 256 + threadIdx.x;
    if (idx < 786432) {
        int l = idx >> 18, rem = idx & 262143;
        int n = rem >> 9, k = rem & 511;
        Wt_mlp[idx] = f2bf(mlp_w[l * 262144 + k * 512 + n]);
    } else if (idx < 786432 + 131072) {
        int rem = idx - 786432;
        int n = rem >> 9, k = rem & 511;
        Wt_out[rem] = f2bf(Wout[k * 256 + n]);
    } else if (idx < 786432 + 131072 + 81920) {
        int rem = idx - (786432 + 131072);
        int n = rem / 160, k = rem % 160;
        Wt_win[rem] = f2bf(k < 132 ? Win[k * 512 + n] : 0.0f);
    } else if (idx < 786432 + 131072 + 81920 + 32768) {
        int rem = idx - (786432 + 131072 + 81920);
        int n = rem >> 9, k = rem & 511;
        Wt_gd[rem] = f2bf(n < 32 ? Wg[k * 32 + n] : Wi[k * 32 + (n - 32)]);
    } else if (idx < 786432 + 131072 + 81920 + 32768 + 16384) {
        int rem = idx - (786432 + 131072 + 81920 + 32768);
        int n = rem >> 5, k = rem & 31;
        Wt_wo[rem] = f2bf(Wo[k * H_ + n]);
    }
}

// ===================== token features =====================
__global__ __launch_bounds__(256) void k_token_feats(
    const int* __restrict__ chars, const float* __restrict__ emb_byte,
    const float* __restrict__ hash_tables, const float* __restrict__ Wq,
    const float* __restrict__ bq, __hip_bfloat16* __restrict__ featb,
    float* __restrict__ hfpre) {
    int wave = threadIdx.x >> 6, lane = threadIdx.x & 63;
    int token = blockIdx.x * 4 + wave;
    int t = token & (T_ - 1);
    int b = token >> 13;
    const int* crow = chars + b * T_;
    int cj = 0;
    if (lane < 16 && (t - lane) >= 0) cj = crow[t - lane];
    int cv[16];
#pragma unroll
    for (int j = 0; j < 16; j++) cv[j] = __shfl(cj, j, 64);
    int acc = 0;
    int hidx[4];
#pragma unroll
    for (int j = 0; j < 16; j++) {
        acc += cv[j] * (1 + 256 * j);
        if (j == 1) hidx[0] = acc & 4095;
        if (j == 3) hidx[1] = acc & 4095;
        if (j == 7) hidx[2] = acc & 4095;
        if (j == 15) hidx[3] = acc & 4095;
    }
    float be = emb_byte[cv[0] * EB_ + lane];
    float se[4];
#pragma unroll
    for (int s = 0; s < 4; s++) se[s] = hash_tables[(s * 4096 + hidx[s]) * E_ + lane];
    float q = bq[lane];
#pragma unroll
    for (int k = 0; k < 64; k++) q += __shfl(be, k, 64) * Wq[k * 64 + lane];
    float sc[4];
#pragma unroll
    for (int s = 0; s < 4; s++) {
        float v = q * se[s];
#pragma unroll
        for (int off = 32; off; off >>= 1) v += __shfl_xor(v, off, 64);
        sc[s] = v * 0.125f;
    }
    float mx = fmaxf(fmaxf(sc[0], sc[1]), fmaxf(sc[2], sc[3]));
    float w0 = expf(sc[0] - mx), w1 = expf(sc[1] - mx), w2 = expf(sc[2] - mx), w3 = expf(sc[3] - mx);
    float inv = 1.0f / (w0 + w1 + w2 + w3);
    float hf = (w0 * se[0] + w1 * se[1] + w2 * se[2] + w3 * se[3]) * inv;
    featb[(size_t)token * FEATP_ + lane] = f2bf(be);
    hfpre[(size_t)token * E_ + lane] = hf;
    if (lane < 32) {
        float m = 0.0f;
        if (lane < 4) {
            int k = 1 << lane;
            m = (t >= k && cv[0] == cv[k]) ? 1.0f : 0.0f;
        }
        featb[(size_t)token * FEATP_ + 128 + lane] = f2bf(m);
    }
}

// ===================== conv -> featb[64:128] =====================
__global__ __launch_bounds__(256) void k_conv(
    const float* __restrict__ hfpre, const float* __restrict__ conv_w,
    const float* __restrict__ conv_b, __hip_bfloat16* __restrict__ featb) {
    int idx = blockIdx.x * 256 + threadIdx.x;
    int e = idx & 63;
    int bt = idx >> 6;
    int t = bt & (T_ - 1);
    float acc = conv_b[e];
#pragma unroll
    for (int k = 0; k < 4; k++) {
        int tt = t - 3 + k;
        if (tt >= 0) acc += hfpre[(size_t)(bt - 3 + k) * E_ + e] * conv_w[e * 4 + k];
    }
    featb[(size_t)bt * FEATP_ + 64 + e] = f2bf(silu_f(acc));
}

// ===================== scan chain =====================
__global__ __launch_bounds__(256) void k_chunk_ab(
    const float* __restrict__ gates, const float* __restrict__ drive,
    float* __restrict__ chA, float* __restrict__ chB) {
    int gid = blockIdx.x * 256 + threadIdx.x;
    int s = gid & 31;
    int n = (gid >> 5) & (NCH_ - 1);
    int b = gid >> 13;
    int base = (b * T_ + n * CHUNK_) * SS_ + s;
    float suml = 0.f, cum_wb = 0.f, cum_a = 1.f;
    for (int i = 0; i < CHUNK_; i++) {
        float g = gates[base + i * SS_];
        float d = drive[base + i * SS_];
        suml += logf(fmaxf(g, 1e-6f));
        cum_a = expf(suml);
        cum_wb += d / fmaxf(cum_a, 1e-8f);
    }
    chA[gid] = cum_a;
    chB[gid] = cum_a * cum_wb;
}

__global__ void k_chunk_scan(const float* __restrict__ chA, const float* __restrict__ chB,
                             float* __restrict__ chH) {
    int tid = threadIdx.x;     // 256 = B*SS
    int b = tid >> 5, s = tid & 31;
    const float* pA = chA + (size_t)b * NCH_ * SS_ + s;
    const float* pB = chB + (size_t)b * NCH_ * SS_ + s;
    float* pH = chH + (size_t)b * NCH_ * SS_ + s;
    float hc = 0.f;
    for (int n = 0; n < NCH_; n += 8) {
        float a[8], bb[8];
#pragma unroll
        for (int i = 0; i < 8; i++) {
            a[i] = pA[(n + i) * SS_];
            bb[i] = pB[(n + i) * SS_];
        }
#pragma unroll
        for (int i = 0; i < 8; i++) {
            pH[(n + i) * SS_] = hc;
            hc = a[i] * hc + bb[i];
        }
    }
}

__global__ __launch_bounds__(256) void k_states(
    const float* __restrict__ gates, const float* __restrict__ drive,
    const float* __restrict__ chH, __hip_bfloat16* __restrict__ states_bf) {
    int gid = blockIdx.x * 256 + threadIdx.x;
    int s = gid & 31;
    int n = (gid >> 5) & (NCH_ - 1);
    int b = gid >> 13;
    int base = (b * T_ + n * CHUNK_) * SS_ + s;
    float hc = chH[gid];
    float suml = 0.f, cum_wb = 0.f;
    for (int i = 0; i < CHUNK_; i++) {
        float g = gates[base + i * SS_];
        float d = drive[base + i * SS_];
        suml += logf(fmaxf(g, 1e-6f));
        float cum_a = expf(suml);
        cum_wb += d / fmaxf(cum_a, 1e-8f);
        states_bf[base + i * SS_] = f2bf(cum_a * (hc + cum_wb));
    }
}

// ===================== launch =====================
extern "C" void kernel_launch(void* const* d_in, const int* in_sizes, int n_in,
                              void* d_out, int out_size, void* d_ws, size_t ws_size,
                              hipStream_t stream) {
    (void)in_sizes; (void)n_in; (void)out_size; (void)ws_size;
    const int*   chars       = (const int*)  d_in[0];
    const float* emb_byte    = (const float*)d_in[1];
    const float* hash_tables = (const float*)d_in[2];
    const float* Wq          = (const float*)d_in[3];
    const float* bq          = (const float*)d_in[4];
    const float* conv_w      = (const float*)d_in[5];
    const float* conv_b      = (const float*)d_in[6];
    const float* Win         = (const float*)d_in[7];
    const float* b_in        = (const float*)d_in[8];
    const float* Wg          = (const float*)d_in[9];
    const float* bg          = (const float*)d_in[10];
    const float* Wi          = (const float*)d_in[11];
    const float* bi          = (const float*)d_in[12];
    const float* Wo          = (const float*)d_in[13];
    const float* bo          = (const float*)d_in[14];
    const float* ln_g        = (const float*)d_in[15];
    const float* ln_b        = (const float*)d_in[16];
    const float* mlp_w       = (const float*)d_in[17];
    const float* mlp_b       = (const float*)d_in[18];
    const float* Wout        = (const float*)d_in[19];
    const float* bout        = (const float*)d_in[20];
    float* out = (float*)d_out;

    const size_t NTOK = (size_t)B_ * T_;  // 65536
    char* p = (char*)d_ws;
    auto alloc = [&](size_t bytes) { void* r = (void*)p; p += (bytes + 255) & ~(size_t)255; return r; };
    __hip_bfloat16* featb = (__hip_bfloat16*)alloc(NTOK * FEATP_ * 2);
    float*          hfpre = (float*)alloc(NTOK * E_ * 4);
    __hip_bfloat16* hbA   = (__hip_bfloat16*)alloc(NTOK * H_ * 2);
    __hip_bfloat16* hbB   = (__hip_bfloat16*)alloc(NTOK * H_ * 2);
    float*          gates = (float*)alloc(NTOK * SS_ * 4);
    float*          drive = (float*)alloc(NTOK * SS_ * 4);
    __hip_bfloat16* states_bf = (__hip_bfloat16*)alloc(NTOK * SS_ * 2);
    float*          chA   = (float*)alloc((size_t)B_ * NCH_ * SS_ * 4);
    float*          chB   = (float*)alloc((size_t)B_ * NCH_ * SS_ * 4);
    float*          chH   = (float*)alloc((size_t)B_ * NCH_ * SS_ * 4);
    __hip_bfloat16* Wt_mlp= (__hip_bfloat16*)alloc(3 * 512 * 512 * 2);
    __hip_bfloat16* Wt_out= (__hip_bfloat16*)alloc(256 * 512 * 2);
    __hip_bfloat16* Wt_win= (__hip_bfloat16*)alloc(512 * FEATP_ * 2);
    __hip_bfloat16* Wt_gd = (__hip_bfloat16*)alloc(64 * 512 * 2);
    __hip_bfloat16* Wt_wo = (__hip_bfloat16*)alloc(512 * SS_ * 2);

    k_prep_w<<<4096, 256, 0, stream>>>(mlp_w, Wout, Win, Wg, Wi, Wo,
                                       Wt_mlp, Wt_out, Wt_win, Wt_gd, Wt_wo);
    k_token_feats<<<NTOK / 4, 256, 0, stream>>>(chars, emb_byte, hash_tables, Wq, bq, featb, hfpre);
    k_conv<<<NTOK * E_ / 256, 256, 0, stream>>>(hfpre, conv_w, conv_b, featb);
    k_win_mfma<<<dim3(NTOK / 128, 4), 256, 0, stream>>>(featb, Wt_win, b_in, hbA);
    k_gates_mfma<<<NTOK / 256, 256, 0, stream>>>(hbA, Wt_gd, bg, bi, gates, drive);
    k_chunk_ab<<<B_ * NCH_ * SS_ / 256, 256, 0, stream>>>(gates, drive, chA, chB);
    k_chunk_scan<<<1, 256, 0, stream>>>(chA, chB, chH);
    k_states<<<B_ * NCH_ * SS_ / 256, 256, 0, stream>>>(gates, drive, chH, states_bf);
    k_womm<<<dim3(NTOK / 128, 4), 256, 0, stream>>>(states_bf, Wt_wo, bo, hbA, hbB);
    k_ln<<<NTOK / 4, 256, 0, stream>>>(hbB, ln_g, ln_b, hbA);
    k_mlp_mfma<<<dim3(NTOK / 128, 4), 256, 0, stream>>>(hbA, Wt_mlp, mlp_b, hbB);
    k_mlp_mfma<<<dim3(NTOK / 128, 4), 256, 0, stream>>>(hbB, Wt_mlp + 262144, mlp_b + 512, hbA);
    k_mlp_mfma<<<dim3(NTOK / 128, 4), 256, 0, stream>>>(hbA, Wt_mlp + 524288, mlp_b + 1024, hbB);
    k_out_mfma<<<dim3(NTOK / 128, 2), 256, 0, stream>>>(hbB, Wt_out, bout, out);
}

// Round 6
// 552.883 us; speedup vs baseline: 2.9827x; 1.0625x over previous
//
#include <hip/hip_runtime.h>
#include <hip/hip_bf16.h>
#include <math.h>

#define B_ 8
#define T_ 8192
#define V_ 256
#define EB_ 64
#define E_ 64
#define H_ 512
#define SS_ 32
#define FEATP_ 160   // padded feature dim (real 132, zero-padded to 160 = 5*32)
#define NCH_ 256
#define CHUNK_ 32

typedef __attribute__((ext_vector_type(8))) short bf8;     // 8 bf16 = 4 VGPRs (MFMA A/B frag)
typedef __attribute__((ext_vector_type(16))) float accv;   // MFMA 32x32 C/D frag

#define AS1(p) (__attribute__((address_space(1))) void*)(void*)(p)
#define AS3(p) (__attribute__((address_space(3))) void*)(void*)(p)

__device__ __forceinline__ float silu_f(float x) { return x / (1.0f + expf(-x)); }
__device__ __forceinline__ float sigm_f(float x) { return 1.0f / (1.0f + expf(-x)); }
__device__ __forceinline__ float bf2f(__hip_bfloat16 v) { return __bfloat162float(v); }
__device__ __forceinline__ __hip_bfloat16 f2bf(float v) { return __float2bfloat16(v); }
__device__ __forceinline__ float us2f(ushort u) {
    union { float f; unsigned int u32; } c; c.u32 = ((unsigned int)u) << 16; return c.f;
}
__device__ __forceinline__ ushort f2us(float v) {
    __hip_bfloat16 t = __float2bfloat16(v);
    return *reinterpret_cast<ushort*>(&t);
}

// ===================== MFMA 128x128-tile GEMM core =====================
template <int KD>
__device__ __forceinline__ void mm128(const __hip_bfloat16* __restrict__ A,
                                      const __hip_bfloat16* __restrict__ Wt,
                                      int m0, int n0, accv (&acc)[2][2]) {
    __shared__ __align__(16) ushort lA[128 * 32];
    __shared__ __align__(16) ushort lB[128 * 32];
    int tid = threadIdx.x;
    int lane = tid & 63, w = tid >> 6;
    int wm = w & 1, wn = w >> 1;
    int c0 = w * 128 + lane;
    int c1 = c0 + 64;
    const ushort* Ab = (const ushort*)A;
    const ushort* Bb = (const ushort*)Wt;
    const ushort* gA0 = Ab + (size_t)(m0 + (c0 >> 2)) * KD + (c0 & 3) * 8;
    const ushort* gA1 = Ab + (size_t)(m0 + (c1 >> 2)) * KD + (c1 & 3) * 8;
    const ushort* gB0 = Bb + (size_t)(n0 + (c0 >> 2)) * KD + (c0 & 3) * 8;
    const ushort* gB1 = Bb + (size_t)(n0 + (c1 >> 2)) * KD + (c1 & 3) * 8;
    ushort* dA0 = &lA[(w * 128) * 8];
    ushort* dA1 = &lA[(w * 128 + 64) * 8];
    ushort* dB0 = &lB[(w * 128) * 8];
    ushort* dB1 = &lB[(w * 128 + 64) * 8];
    const ushort* pa = &lA[(64 * wm + (lane & 31)) * 32 + (lane >> 5) * 8];
    const ushort* pb = &lB[(64 * wn + (lane & 31)) * 32 + (lane >> 5) * 8];

    for (int kt = 0; kt < KD; kt += 32) {
        __builtin_amdgcn_global_load_lds(AS1(gA0 + kt), AS3(dA0), 16, 0, 0);
        __builtin_amdgcn_global_load_lds(AS1(gA1 + kt), AS3(dA1), 16, 0, 0);
        __builtin_amdgcn_global_load_lds(AS1(gB0 + kt), AS3(dB0), 16, 0, 0);
        __builtin_amdgcn_global_load_lds(AS1(gB1 + kt), AS3(dB1), 16, 0, 0);
        __syncthreads();
#pragma unroll
        for (int ks = 0; ks < 2; ks++) {
            bf8 a0 = *(const bf8*)(pa + ks * 16);
            bf8 a1 = *(const bf8*)(pa + 32 * 32 + ks * 16);
            bf8 b0 = *(const bf8*)(pb + ks * 16);
            bf8 b1 = *(const bf8*)(pb + 32 * 32 + ks * 16);
            acc[0][0] = __builtin_amdgcn_mfma_f32_32x32x16_bf16(a0, b0, acc[0][0], 0, 0, 0);
            acc[0][1] = __builtin_amdgcn_mfma_f32_32x32x16_bf16(a0, b1, acc[0][1], 0, 0, 0);
            acc[1][0] = __builtin_amdgcn_mfma_f32_32x32x16_bf16(a1, b0, acc[1][0], 0, 0, 0);
            acc[1][1] = __builtin_amdgcn_mfma_f32_32x32x16_bf16(a1, b1, acc[1][1], 0, 0, 0);
        }
        __syncthreads();
    }
}

__device__ __forceinline__ void zero_acc(accv (&acc)[2][2]) {
#pragma unroll
    for (int i = 0; i < 2; i++)
#pragma unroll
        for (int j = 0; j < 2; j++)
#pragma unroll
            for (int r = 0; r < 16; r++) acc[i][j][r] = 0.0f;
}

#define CD_ROW(r, lane) (((r) & 3) + 8 * ((r) >> 2) + 4 * ((lane) >> 5))

// ---------------- MLP residual block: hout = hin + silu(hin @ W + b)
__global__ __launch_bounds__(256) void k_mlp_mfma(const __hip_bfloat16* __restrict__ hin,
                                                  const __hip_bfloat16* __restrict__ Wt,
                                                  const float* __restrict__ bias,
                                                  __hip_bfloat16* __restrict__ hout) {
    accv acc[2][2];
    zero_acc(acc);
    int lane = threadIdx.x & 63, w = threadIdx.x >> 6, wm = w & 1, wn = w >> 1;
    int m0 = blockIdx.x * 128, n0 = blockIdx.y * 128;
    mm128<H_>(hin, Wt, m0, n0, acc);
#pragma unroll
    for (int i = 0; i < 2; i++)
#pragma unroll
        for (int j = 0; j < 2; j++) {
            int col = n0 + 64 * wn + 32 * j + (lane & 31);
            float bv = bias[col];
#pragma unroll
            for (int r = 0; r < 16; r++) {
                int row = m0 + 64 * wm + 32 * i + CD_ROW(r, lane);
                float v = acc[i][j][r] + bv;
                float res = bf2f(hin[(size_t)row * H_ + col]);
                hout[(size_t)row * H_ + col] = f2bf(res + silu_f(v));
            }
        }
}

// ---------------- Win: hb = bf16(silu(featb @ Win + b_in)), KD=160
__global__ __launch_bounds__(256) void k_win_mfma(const __hip_bfloat16* __restrict__ featb,
                                                  const __hip_bfloat16* __restrict__ Wt,
                                                  const float* __restrict__ bias,
                                                  __hip_bfloat16* __restrict__ hb) {
    accv acc[2][2];
    zero_acc(acc);
    int lane = threadIdx.x & 63, w = threadIdx.x >> 6, wm = w & 1, wn = w >> 1;
    int m0 = blockIdx.x * 128, n0 = blockIdx.y * 128;
    mm128<FEATP_>(featb, Wt, m0, n0, acc);
#pragma unroll
    for (int i = 0; i < 2; i++)
#pragma unroll
        for (int j = 0; j < 2; j++) {
            int col = n0 + 64 * wn + 32 * j + (lane & 31);
            float bv = bias[col];
#pragma unroll
            for (int r = 0; r < 16; r++) {
                int row = m0 + 64 * wm + 32 * i + CD_ROW(r, lane);
                hb[(size_t)row * H_ + col] = f2bf(silu_f(acc[i][j][r] + bv));
            }
        }
}

// ---------------- womm: tmp = hb + states_bf @ Wo^T + bo  (K=32 single tile)
__global__ __launch_bounds__(256) void k_womm(const __hip_bfloat16* __restrict__ states_bf,
                                              const __hip_bfloat16* __restrict__ Wt_wo,
                                              const float* __restrict__ bo,
                                              const __hip_bfloat16* __restrict__ hb,
                                              __hip_bfloat16* __restrict__ tmp) {
    accv acc[2][2];
    zero_acc(acc);
    int lane = threadIdx.x & 63, w = threadIdx.x >> 6, wm = w & 1, wn = w >> 1;
    int m0 = blockIdx.x * 128, n0 = blockIdx.y * 128;
    mm128<SS_>(states_bf, Wt_wo, m0, n0, acc);
#pragma unroll
    for (int i = 0; i < 2; i++)
#pragma unroll
        for (int j = 0; j < 2; j++) {
            int col = n0 + 64 * wn + 32 * j + (lane & 31);
            float bv = bo[col];
#pragma unroll
            for (int r = 0; r < 16; r++) {
                int row = m0 + 64 * wm + 32 * i + CD_ROW(r, lane);
                float res = bf2f(hb[(size_t)row * H_ + col]);
                tmp[(size_t)row * H_ + col] = f2bf(res + acc[i][j][r] + bv);
            }
        }
}

// ---------------- LN: one wave per token, 8 cols/lane
__global__ __launch_bounds__(256) void k_ln(const __hip_bfloat16* __restrict__ tmp,
                                            const float* __restrict__ ln_g,
                                            const float* __restrict__ ln_b,
                                            __hip_bfloat16* __restrict__ hb) {
    int wave = threadIdx.x >> 6, lane = threadIdx.x & 63;
    int token = blockIdx.x * 4 + wave;
    const ushort* row = (const ushort*)(tmp + (size_t)token * H_) + lane * 8;
    bf8 xv = *(const bf8*)row;
    float x[8];
    float sm = 0.f, sq = 0.f;
#pragma unroll
    for (int i = 0; i < 8; i++) {
        x[i] = us2f((ushort)xv[i]);
        sm += x[i];
        sq += x[i] * x[i];
    }
#pragma unroll
    for (int off = 32; off; off >>= 1) {
        sm += __shfl_xor(sm, off, 64);
        sq += __shfl_xor(sq, off, 64);
    }
    float mu = sm * (1.0f / 512.0f);
    float var = sq * (1.0f / 512.0f) - mu * mu;
    float rstd = rsqrtf(fmaxf(var, 0.0f) + 1e-5f);
    float4 g0 = *(const float4*)(ln_g + lane * 8);
    float4 g1 = *(const float4*)(ln_g + lane * 8 + 4);
    float4 b0 = *(const float4*)(ln_b + lane * 8);
    float4 b1 = *(const float4*)(ln_b + lane * 8 + 4);
    float gg[8] = {g0.x, g0.y, g0.z, g0.w, g1.x, g1.y, g1.z, g1.w};
    float bb[8] = {b0.x, b0.y, b0.z, b0.w, b1.x, b1.y, b1.z, b1.w};
    bf8 o;
#pragma unroll
    for (int i = 0; i < 8; i++) o[i] = (short)f2us((x[i] - mu) * rstd * gg[i] + bb[i]);
    *(bf8*)((ushort*)(hb + (size_t)token * H_) + lane * 8) = o;
}

// ---------------- Out: out = hb @ Wout + bout (fp32 out, N=256)
__global__ __launch_bounds__(256) void k_out_mfma(const __hip_bfloat16* __restrict__ hb,
                                                  const __hip_bfloat16* __restrict__ Wt,
                                                  const float* __restrict__ bout,
                                                  float* __restrict__ out) {
    accv acc[2][2];
    zero_acc(acc);
    int lane = threadIdx.x & 63, w = threadIdx.x >> 6, wm = w & 1, wn = w >> 1;
    int m0 = blockIdx.x * 128, n0 = blockIdx.y * 128;
    mm128<H_>(hb, Wt, m0, n0, acc);
#pragma unroll
    for (int i = 0; i < 2; i++)
#pragma unroll
        for (int j = 0; j < 2; j++) {
            int col = n0 + 64 * wn + 32 * j + (lane & 31);
            float bv = bout[col];
#pragma unroll
            for (int r = 0; r < 16; r++) {
                int row = m0 + 64 * wm + 32 * i + CD_ROW(r, lane);
                out[(size_t)row * V_ + col] = acc[i][j][r] + bv;
            }
        }
}

// ---------------- gates/drive: [g|i] = hb @ [Wg|Wi]; tile 256x64, K=512
__global__ __launch_bounds__(256) void k_gates_mfma(const __hip_bfloat16* __restrict__ hb,
                                                    const __hip_bfloat16* __restrict__ Wt_gd,
                                                    const float* __restrict__ bg,
                                                    const float* __restrict__ bi,
                                                    float* __restrict__ gates,
                                                    float* __restrict__ drive) {
    __shared__ __align__(16) ushort lA[256 * 32];
    __shared__ __align__(16) ushort lB[64 * 32];
    int tid = threadIdx.x, lane = tid & 63, w = tid >> 6;
    int m0 = blockIdx.x * 256;
    accv acc[2][2];
    zero_acc(acc);
    const ushort* Ab = (const ushort*)hb;
    const ushort* Bb = (const ushort*)Wt_gd;
    const ushort* pa = &lA[(64 * w + (lane & 31)) * 32 + (lane >> 5) * 8];
    const ushort* pb = &lB[((lane & 31)) * 32 + (lane >> 5) * 8];
    int cb = w * 64 + lane;
    const ushort* gB = Bb + (size_t)(cb >> 2) * H_ + (cb & 3) * 8;
    for (int kt = 0; kt < H_; kt += 32) {
#pragma unroll
        for (int j = 0; j < 4; j++) {
            int c = w * 256 + j * 64 + lane;
            __builtin_amdgcn_global_load_lds(
                AS1(Ab + (size_t)(m0 + (c >> 2)) * H_ + (c & 3) * 8 + kt),
                AS3(&lA[(w * 256 + j * 64) * 8]), 16, 0, 0);
        }
        __builtin_amdgcn_global_load_lds(AS1(gB + kt), AS3(&lB[(w * 64) * 8]), 16, 0, 0);
        __syncthreads();
#pragma unroll
        for (int ks = 0; ks < 2; ks++) {
            bf8 a0 = *(const bf8*)(pa + ks * 16);
            bf8 a1 = *(const bf8*)(pa + 32 * 32 + ks * 16);
            bf8 b0 = *(const bf8*)(pb + ks * 16);
            bf8 b1 = *(const bf8*)(pb + 32 * 32 + ks * 16);
            acc[0][0] = __builtin_amdgcn_mfma_f32_32x32x16_bf16(a0, b0, acc[0][0], 0, 0, 0);
            acc[0][1] = __builtin_amdgcn_mfma_f32_32x32x16_bf16(a0, b1, acc[0][1], 0, 0, 0);
            acc[1][0] = __builtin_amdgcn_mfma_f32_32x32x16_bf16(a1, b0, acc[1][0], 0, 0, 0);
            acc[1][1] = __builtin_amdgcn_mfma_f32_32x32x16_bf16(a1, b1, acc[1][1], 0, 0, 0);
        }
        __syncthreads();
    }
    int c = lane & 31;
    float bgv = bg[c], biv = bi[c];
#pragma unroll
    for (int i = 0; i < 2; i++)
#pragma unroll
        for (int r = 0; r < 16; r++) {
            int row = m0 + 64 * w + 32 * i + CD_ROW(r, lane);
            float g = sigm_f(acc[i][0][r] + bgv);
            float d = (1.0f - g) * (acc[i][1][r] + biv);
            gates[(size_t)row * SS_ + c] = g;
            drive[(size_t)row * SS_ + c] = d;
        }
}

// ===================== weight prep: bf16 + transpose + Qtab =====================
__global__ __launch_bounds__(256) void k_prep_w(const float* __restrict__ mlp_w,
                                                const float* __restrict__ Wout,
                                                const float* __restrict__ Win,
                                                const float* __restrict__ Wg,
                                                const float* __restrict__ Wi,
                                                const float* __restrict__ Wo,
                                                const float* __restrict__ Wq,
                                                const float* __restrict__ bq,
                                                const float* __restrict__ emb_byte,
                                                __hip_bfloat16* __restrict__ Wt_mlp,
                                                __hip_bfloat16* __restrict__ Wt_out,
                                                __hip_bfloat16* __restrict__ Wt_win,
                                                __hip_bfloat16* __restrict__ Wt_gd,
                                                __hip_bfloat16* __restrict__ Wt_wo,
                                                float* __restrict__ Qtab) {
    int idx = blockIdx.x * 256 + threadIdx.x;
    if (idx < 786432) {
        int l = idx >> 18, rem = idx & 262143;
        int n = rem >> 9, k = rem & 511;
        Wt_mlp[idx] = f2bf(mlp_w[l * 262144 + k * 512 + n]);
    } else if (idx < 786432 + 131072) {
        int rem = idx - 786432;
        int n = rem >> 9, k = rem & 511;
        Wt_out[rem] = f2bf(Wout[k * 256 + n]);
    } else if (idx < 786432 + 131072 + 81920) {
        int rem = idx - (786432 + 131072);
        int n = rem / 160, k = rem % 160;
        Wt_win[rem] = f2bf(k < 132 ? Win[k * 512 + n] : 0.0f);
    } else if (idx < 786432 + 131072 + 81920 + 32768) {
        int rem = idx - (786432 + 131072 + 81920);
        int n = rem >> 9, k = rem & 511;
        Wt_gd[rem] = f2bf(n < 32 ? Wg[k * 32 + n] : Wi[k * 32 + (n - 32)]);
    } else if (idx < 786432 + 131072 + 81920 + 32768 + 16384) {
        int rem = idx - (786432 + 131072 + 81920 + 32768);
        int n = rem >> 5, k = rem & 31;
        Wt_wo[rem] = f2bf(Wo[k * H_ + n]);
    } else if (idx < 786432 + 131072 + 81920 + 32768 + 16384 + 16384) {
        int rem = idx - (786432 + 131072 + 81920 + 32768 + 16384);
        int c = rem >> 6, e = rem & 63;
        float a = bq[e];
#pragma unroll 8
        for (int k = 0; k < 64; k++) a += emb_byte[c * 64 + k] * Wq[k * 64 + e];
        Qtab[rem] = a * 0.125f;   // fold 1/sqrt(E) score scale
    }
}

// ===================== token features (Qtab-based, no matvec) =====================
__global__ __launch_bounds__(256) void k_token_feats(
    const int* __restrict__ chars, const float* __restrict__ emb_byte,
    const float* __restrict__ hash_tables, const float* __restrict__ Qtab,
    __hip_bfloat16* __restrict__ featb, float* __restrict__ hfpre) {
    int wave = threadIdx.x >> 6, lane = threadIdx.x & 63;
    int token = blockIdx.x * 4 + wave;
    int t = token & (T_ - 1);
    int b = token >> 13;
    const int* crow = chars + b * T_;
    int cv[16];
#pragma unroll
    for (int j = 0; j < 16; j++) cv[j] = (t >= j) ? crow[t - j] : 0;   // wave-uniform broadcast loads
    int acc = 0;
    int hidx[4];
#pragma unroll
    for (int j = 0; j < 16; j++) {
        acc += cv[j] * (1 + 256 * j);
        if (j == 1) hidx[0] = acc & 4095;
        if (j == 3) hidx[1] = acc & 4095;
        if (j == 7) hidx[2] = acc & 4095;
        if (j == 15) hidx[3] = acc & 4095;
    }
    int c0 = cv[0];
    float be = emb_byte[c0 * EB_ + lane];
    float q = Qtab[c0 * 64 + lane];            // pre-scaled by 0.125
    float se[4];
#pragma unroll
    for (int s = 0; s < 4; s++) se[s] = hash_tables[(s * 4096 + hidx[s]) * E_ + lane];
    float sc[4];
#pragma unroll
    for (int s = 0; s < 4; s++) {
        float v = q * se[s];
#pragma unroll
        for (int off = 32; off; off >>= 1) v += __shfl_xor(v, off, 64);
        sc[s] = v;
    }
    float mx = fmaxf(fmaxf(sc[0], sc[1]), fmaxf(sc[2], sc[3]));
    float w0 = expf(sc[0] - mx), w1 = expf(sc[1] - mx), w2 = expf(sc[2] - mx), w3 = expf(sc[3] - mx);
    float inv = 1.0f / (w0 + w1 + w2 + w3);
    float hf = (w0 * se[0] + w1 * se[1] + w2 * se[2] + w3 * se[3]) * inv;
    featb[(size_t)token * FEATP_ + lane] = f2bf(be);
    hfpre[(size_t)token * E_ + lane] = hf;
    if (lane < 32) {
        float m = 0.0f;
        if (lane < 4) {
            int k = 1 << lane;
            m = (t >= k && c0 == cv[k]) ? 1.0f : 0.0f;
        }
        featb[(size_t)token * FEATP_ + 128 + lane] = f2bf(m);
    }
}

// ===================== conv -> featb[64:128] =====================
__global__ __launch_bounds__(256) void k_conv(
    const float* __restrict__ hfpre, const float* __restrict__ conv_w,
    const float* __restrict__ conv_b, __hip_bfloat16* __restrict__ featb) {
    int idx = blockIdx.x * 256 + threadIdx.x;
    int e = idx & 63;
    int bt = idx >> 6;
    int t = bt & (T_ - 1);
    float acc = conv_b[e];
#pragma unroll
    for (int k = 0; k < 4; k++) {
        int tt = t - 3 + k;
        if (tt >= 0) acc += hfpre[(size_t)(bt - 3 + k) * E_ + e] * conv_w[e * 4 + k];
    }
    featb[(size_t)bt * FEATP_ + 64 + e] = f2bf(silu_f(acc));
}

// ===================== scan chain =====================
__global__ __launch_bounds__(256) void k_chunk_ab(
    const float* __restrict__ gates, const float* __restrict__ drive,
    float* __restrict__ chA, float* __restrict__ chB) {
    int gid = blockIdx.x * 256 + threadIdx.x;
    int s = gid & 31;
    int n = (gid >> 5) & (NCH_ - 1);
    int b = gid >> 13;
    int base = (b * T_ + n * CHUNK_) * SS_ + s;
    float suml = 0.f, cum_wb = 0.f, cum_a = 1.f;
    for (int i = 0; i < CHUNK_; i++) {
        float g = gates[base + i * SS_];
        float d = drive[base + i * SS_];
        suml += logf(fmaxf(g, 1e-6f));
        cum_a = expf(suml);
        cum_wb += d / fmaxf(cum_a, 1e-8f);
    }
    chA[gid] = cum_a;
    chB[gid] = cum_a * cum_wb;
}

__global__ void k_chunk_scan(const float* __restrict__ chA, const float* __restrict__ chB,
                             float* __restrict__ chH) {
    int tid = threadIdx.x;     // 256 = B*SS
    int b = tid >> 5, s = tid & 31;
    const float* pA = chA + (size_t)b * NCH_ * SS_ + s;
    const float* pB = chB + (size_t)b * NCH_ * SS_ + s;
    float* pH = chH + (size_t)b * NCH_ * SS_ + s;
    float hc = 0.f;
    for (int n = 0; n < NCH_; n += 8) {
        float a[8], bb[8];
#pragma unroll
        for (int i = 0; i < 8; i++) {
            a[i] = pA[(n + i) * SS_];
            bb[i] = pB[(n + i) * SS_];
        }
#pragma unroll
        for (int i = 0; i < 8; i++) {
            pH[(n + i) * SS_] = hc;
            hc = a[i] * hc + bb[i];
        }
    }
}

__global__ __launch_bounds__(256) void k_states(
    const float* __restrict__ gates, const float* __restrict__ drive,
    const float* __restrict__ chH, __hip_bfloat16* __restrict__ states_bf) {
    int gid = blockIdx.x * 256 + threadIdx.x;
    int s = gid & 31;
    int n = (gid >> 5) & (NCH_ - 1);
    int b = gid >> 13;
    int base = (b * T_ + n * CHUNK_) * SS_ + s;
    float hc = chH[gid];
    float suml = 0.f, cum_wb = 0.f;
    for (int i = 0; i < CHUNK_; i++) {
        float g = gates[base + i * SS_];
        float d = drive[base + i * SS_];
        suml += logf(fmaxf(g, 1e-6f));
        float cum_a = expf(suml);
        cum_wb += d / fmaxf(cum_a, 1e-8f);
        states_bf[base + i * SS_] = f2bf(cum_a * (hc + cum_wb));
    }
}

// ===================== launch =====================
extern "C" void kernel_launch(void* const* d_in, const int* in_sizes, int n_in,
                              void* d_out, int out_size, void* d_ws, size_t ws_size,
                              hipStream_t stream) {
    (void)in_sizes; (void)n_in; (void)out_size; (void)ws_size;
    const int*   chars       = (const int*)  d_in[0];
    const float* emb_byte    = (const float*)d_in[1];
    const float* hash_tables = (const float*)d_in[2];
    const float* Wq          = (const float*)d_in[3];
    const float* bq          = (const float*)d_in[4];
    const float* conv_w      = (const float*)d_in[5];
    const float* conv_b      = (const float*)d_in[6];
    const float* Win         = (const float*)d_in[7];
    const float* b_in        = (const float*)d_in[8];
    const float* Wg          = (const float*)d_in[9];
    const float* bg          = (const float*)d_in[10];
    const float* Wi          = (const float*)d_in[11];
    const float* bi          = (const float*)d_in[12];
    const float* Wo          = (const float*)d_in[13];
    const float* bo          = (const float*)d_in[14];
    const float* ln_g        = (const float*)d_in[15];
    const float* ln_b        = (const float*)d_in[16];
    const float* mlp_w       = (const float*)d_in[17];
    const float* mlp_b       = (const float*)d_in[18];
    const float* Wout        = (const float*)d_in[19];
    const float* bout        = (const float*)d_in[20];
    float* out = (float*)d_out;

    const size_t NTOK = (size_t)B_ * T_;  // 65536
    char* p = (char*)d_ws;
    auto alloc = [&](size_t bytes) { void* r = (void*)p; p += (bytes + 255) & ~(size_t)255; return r; };
    __hip_bfloat16* featb = (__hip_bfloat16*)alloc(NTOK * FEATP_ * 2);
    float*          hfpre = (float*)alloc(NTOK * E_ * 4);
    __hip_bfloat16* hbA   = (__hip_bfloat16*)alloc(NTOK * H_ * 2);
    __hip_bfloat16* hbB   = (__hip_bfloat16*)alloc(NTOK * H_ * 2);
    float*          gates = (float*)alloc(NTOK * SS_ * 4);
    float*          drive = (float*)alloc(NTOK * SS_ * 4);
    __hip_bfloat16* states_bf = (__hip_bfloat16*)alloc(NTOK * SS_ * 2);
    float*          chA   = (float*)alloc((size_t)B_ * NCH_ * SS_ * 4);
    float*          chB   = (float*)alloc((size_t)B_ * NCH_ * SS_ * 4);
    float*          chH   = (float*)alloc((size_t)B_ * NCH_ * SS_ * 4);
    __hip_bfloat16* Wt_mlp= (__hip_bfloat16*)alloc(3 * 512 * 512 * 2);
    __hip_bfloat16* Wt_out= (__hip_bfloat16*)alloc(256 * 512 * 2);
    __hip_bfloat16* Wt_win= (__hip_bfloat16*)alloc(512 * FEATP_ * 2);
    __hip_bfloat16* Wt_gd = (__hip_bfloat16*)alloc(64 * 512 * 2);
    __hip_bfloat16* Wt_wo = (__hip_bfloat16*)alloc(512 * SS_ * 2);
    float*          Qtab  = (float*)alloc(256 * 64 * 4);

    k_prep_w<<<4160, 256, 0, stream>>>(mlp_w, Wout, Win, Wg, Wi, Wo, Wq, bq, emb_byte,
                                       Wt_mlp, Wt_out, Wt_win, Wt_gd, Wt_wo, Qtab);
    k_token_feats<<<NTOK / 4, 256, 0, stream>>>(chars, emb_byte, hash_tables, Qtab, featb, hfpre);
    k_conv<<<NTOK * E_ / 256, 256, 0, stream>>>(hfpre, conv_w, conv_b, featb);
    k_win_mfma<<<dim3(NTOK / 128, 4), 256, 0, stream>>>(featb, Wt_win, b_in, hbA);
    k_gates_mfma<<<NTOK / 256, 256, 0, stream>>>(hbA, Wt_gd, bg, bi, gates, drive);
    k_chunk_ab<<<B_ * NCH_ * SS_ / 256, 256, 0, stream>>>(gates, drive, chA, chB);
    k_chunk_scan<<<1, 256, 0, stream>>>(chA, chB, chH);
    k_states<<<B_ * NCH_ * SS_ / 256, 256, 0, stream>>>(gates, drive, chH, states_bf);
    k_womm<<<dim3(NTOK / 128, 4), 256, 0, stream>>>(states_bf, Wt_wo, bo, hbA, hbB);
    k_ln<<<NTOK / 4, 256, 0, stream>>>(hbB, ln_g, ln_b, hbA);
    k_mlp_mfma<<<dim3(NTOK / 128, 4), 256, 0, stream>>>(hbA, Wt_mlp, mlp_b, hbB);
    k_mlp_mfma<<<dim3(NTOK / 128, 4), 256, 0, stream>>>(hbB, Wt_mlp + 262144, mlp_b + 512, hbA);
    k_mlp_mfma<<<dim3(NTOK / 128, 4), 256, 0, stream>>>(hbA, Wt_mlp + 524288, mlp_b + 1024, hbB);
    k_out_mfma<<<dim3(NTOK / 128, 2), 256, 0, stream>>>(hbB, Wt_out, bout, out);
}